// Round 1
// baseline (5900.109 us; speedup 1.0000x reference)
//
#include <hip/hip_runtime.h>

#define NB 4
#define F 32          // F_IN == F_OUT == 32
#define EPB 512       // edges per block in main kernel

// d_ws int32 layout
#define WS_COUNTS  0   // [9]
#define WS_CELLOFF 16  // [10]
#define WS_BLKOFF  32  // [10]
#define WS_CURSOR  48  // [9]
#define WS_SORTED  64  // [E]

__device__ __forceinline__ int cell_of(float ax, float ay) {
    float tx = (ax + 1.0f) * 1.5f;
    float ty = (ay + 1.0f) * 1.5f;
    int kx = (int)tx; if (kx > 2) kx = 2; if (kx < 0) kx = 0;
    int ky = (int)ty; if (ky > 2) ky = 2; if (ky < 0) ky = 0;
    return kx * 3 + ky;
}

__global__ void count_kernel(const float* __restrict__ attr, int E, int* __restrict__ ws) {
    int e = blockIdx.x * blockDim.x + threadIdx.x;
    if (e >= E) return;
    int c = cell_of(attr[2 * e], attr[2 * e + 1]);
    atomicAdd(&ws[WS_COUNTS + c], 1);
}

__global__ void scan_kernel(int* __restrict__ ws) {
    if (threadIdx.x != 0 || blockIdx.x != 0) return;
    int off = 0, boff = 0;
    for (int c = 0; c < 9; ++c) {
        int cnt = ws[WS_COUNTS + c];
        ws[WS_CELLOFF + c] = off;
        ws[WS_CURSOR + c]  = off;
        ws[WS_BLKOFF + c]  = boff;
        off  += cnt;
        boff += (cnt + EPB - 1) / EPB;
    }
    ws[WS_CELLOFF + 9] = off;
    ws[WS_BLKOFF + 9]  = boff;
}

__global__ void scatter_kernel(const float* __restrict__ attr, int E, int* __restrict__ ws) {
    int e = blockIdx.x * blockDim.x + threadIdx.x;
    if (e >= E) return;
    int c = cell_of(attr[2 * e], attr[2 * e + 1]);
    int pos = atomicAdd(&ws[WS_CURSOR + c], 1);
    ws[WS_SORTED + pos] = e;
}

#define FMA4(FE, I)                              \
    acc0 = fmaf((FE), wr[0][(I)], acc0);         \
    acc1 = fmaf((FE), wr[1][(I)], acc1);         \
    acc2 = fmaf((FE), wr[2][(I)], acc2);         \
    acc3 = fmaf((FE), wr[3][(I)], acc3);

__global__ __launch_bounds__(256) void bconv_main(
    const float* __restrict__ x_j, const int* __restrict__ ei,
    const float* __restrict__ attr, const float* __restrict__ weight,
    const int* __restrict__ ws, float* __restrict__ out, int E)
{
    // map block -> (cell, local chunk)
    int b = blockIdx.x;
    const int* blkoff = ws + WS_BLKOFF;
    if (b >= blkoff[9]) return;
    int c = 0;
    #pragma unroll
    for (int q = 1; q < 9; ++q) c += (b >= blkoff[q]) ? 1 : 0;
    int kx0 = c / 3, ky0 = c - 3 * (c / 3);
    int local  = b - blkoff[c];
    int cstart = ws[WS_CELLOFF + c];
    int cend   = ws[WS_CELLOFF + c + 1];
    int pstart = cstart + local * EPB;
    int pend   = min(pstart + EPB, cend);

    __shared__ float wl[4][F][F];    // 16 KB: this cell's 4 k-slices, [kk][i][o]
    __shared__ float featl[8][F];    // 1 KB: per-half-wave feature rows

    int t = threadIdx.x;
    // stage weight cell into LDS (coalesced float4)
    #pragma unroll
    for (int r = 0; r < 4; ++r) {
        int k = (kx0 + (r >> 1)) * NB + (ky0 + (r & 1));
        float4 v = reinterpret_cast<const float4*>(weight + (size_t)k * F * F)[t];
        reinterpret_cast<float4*>(&wl[r][0][0])[t] = v;
    }
    __syncthreads();

    int lane  = t & 31;
    int eslot = t >> 5;

    // per-thread register copy: wr[kk][i] = W[k(kk)][i][lane]
    float wr[4][F];
    #pragma unroll
    for (int kk = 0; kk < 4; ++kk)
        #pragma unroll
        for (int i = 0; i < F; ++i)
            wr[kk][i] = wl[kk][i][lane];

    int p = pstart + eslot;
    if (p >= pend) return;   // uniform per half-wave

    // load first edge
    int e    = ws[WS_SORTED + p];
    int dst  = ei[e];
    int srcn = ei[E + e];
    float ax = attr[2 * e], ay = attr[2 * e + 1];
    float fv = x_j[(size_t)srcn * F + lane];

    while (true) {
        featl[eslot][lane] = fv;

        // prefetch next edge (hide gather latency under FMA chain)
        int pn = p + 8;
        bool nvalid = pn < pend;
        int dst2 = 0, srcn2 = 0; float ax2 = 0.f, ay2 = 0.f, fv2 = 0.f;
        if (nvalid) {
            int e2 = ws[WS_SORTED + pn];
            dst2 = ei[e2]; srcn2 = ei[E + e2];
            ax2  = attr[2 * e2]; ay2 = attr[2 * e2 + 1];
            fv2  = x_j[(size_t)srcn2 * F + lane];
        }

        float fx = (ax + 1.0f) * 1.5f - (float)kx0;  // in [0,1]
        float fy = (ay + 1.0f) * 1.5f - (float)ky0;
        float bx0 = 1.0f - fx, bx1 = fx;
        float by0 = 1.0f - fy, by1 = fy;

        float acc0 = 0.f, acc1 = 0.f, acc2 = 0.f, acc3 = 0.f;
        const float4* f4 = reinterpret_cast<const float4*>(&featl[eslot][0]);
        #pragma unroll
        for (int j = 0; j < 8; ++j) {
            float4 f = f4[j];
            FMA4(f.x, 4 * j + 0)
            FMA4(f.y, 4 * j + 1)
            FMA4(f.z, 4 * j + 2)
            FMA4(f.w, 4 * j + 3)
        }
        float msg = (bx0 * by0) * acc0 + (bx0 * by1) * acc1
                  + (bx1 * by0) * acc2 + (bx1 * by1) * acc3;
        atomicAdd(&out[(size_t)dst * F + lane], msg);

        if (!nvalid) break;
        p = pn; dst = dst2; ax = ax2; ay = ay2; fv = fv2;
        (void)srcn2;
    }
}

// Fallback if ws is too small for bucketing: full 64KB weight in LDS, dynamic cell.
__global__ __launch_bounds__(256) void bconv_fallback(
    const float* __restrict__ x_j, const int* __restrict__ ei,
    const float* __restrict__ attr, const float* __restrict__ weight,
    float* __restrict__ out, int E)
{
    __shared__ float wl[16 * F * F];   // 64 KB
    __shared__ float featl[8][F];
    for (int idx = threadIdx.x; idx < 4096; idx += 256)
        reinterpret_cast<float4*>(wl)[idx] = reinterpret_cast<const float4*>(weight)[idx];
    __syncthreads();

    int lane = threadIdx.x & 31, eslot = threadIdx.x >> 5;
    for (int p = blockIdx.x * 8 + eslot; p < E; p += gridDim.x * 8) {
        int dst = ei[p], srcn = ei[E + p];
        float ax = attr[2 * p], ay = attr[2 * p + 1];
        featl[eslot][lane] = x_j[(size_t)srcn * F + lane];
        float tx = (ax + 1.0f) * 1.5f, ty = (ay + 1.0f) * 1.5f;
        int kx0 = (int)tx; if (kx0 > 2) kx0 = 2; if (kx0 < 0) kx0 = 0;
        int ky0 = (int)ty; if (ky0 > 2) ky0 = 2; if (ky0 < 0) ky0 = 0;
        float fx = tx - kx0, fy = ty - ky0;
        float bc[4] = { (1.0f - fx) * (1.0f - fy), (1.0f - fx) * fy,
                        fx * (1.0f - fy), fx * fy };
        float msg = 0.f;
        const float4* f4 = reinterpret_cast<const float4*>(&featl[eslot][0]);
        #pragma unroll
        for (int kk = 0; kk < 4; ++kk) {
            int k = (kx0 + (kk >> 1)) * NB + (ky0 + (kk & 1));
            const float* wk = wl + k * F * F;
            float acc = 0.f;
            #pragma unroll
            for (int j = 0; j < 8; ++j) {
                float4 f = f4[j];
                acc = fmaf(f.x, wk[(4 * j + 0) * F + lane], acc);
                acc = fmaf(f.y, wk[(4 * j + 1) * F + lane], acc);
                acc = fmaf(f.z, wk[(4 * j + 2) * F + lane], acc);
                acc = fmaf(f.w, wk[(4 * j + 3) * F + lane], acc);
            }
            msg = fmaf(bc[kk], acc, msg);
        }
        atomicAdd(&out[(size_t)dst * F + lane], msg);
    }
}

extern "C" void kernel_launch(void* const* d_in, const int* in_sizes, int n_in,
                              void* d_out, int out_size, void* d_ws, size_t ws_size,
                              hipStream_t stream) {
    const float* x_j    = (const float*)d_in[1];
    const int*   ei     = (const int*)d_in[2];
    const float* attr   = (const float*)d_in[3];
    const float* weight = (const float*)d_in[4];
    float* out = (float*)d_out;
    int E = in_sizes[2] / 2;

    hipMemsetAsync(d_out, 0, (size_t)out_size * sizeof(float), stream);

    size_t ws_need = (size_t)(64 + E) * sizeof(int);
    if (ws_size >= ws_need) {
        int* ws = (int*)d_ws;
        hipMemsetAsync(ws, 0, 64 * sizeof(int), stream);
        int nb = (E + 255) / 256;
        count_kernel<<<nb, 256, 0, stream>>>(attr, E, ws);
        scan_kernel<<<1, 64, 0, stream>>>(ws);
        scatter_kernel<<<nb, 256, 0, stream>>>(attr, E, ws);
        int nblk = (E + EPB - 1) / EPB + 9;
        bconv_main<<<nblk, 256, 0, stream>>>(x_j, ei, attr, weight, ws, out, E);
    } else {
        bconv_fallback<<<2048, 256, 0, stream>>>(x_j, ei, attr, weight, out, E);
    }
}

// Round 2
// 252.935 us; speedup vs baseline: 23.3266x; 23.3266x over previous
//
#include <hip/hip_runtime.h>

#define NB 4
#define F 32          // F_IN == F_OUT == 32
#define EPB 512       // edges per block in main kernel
#define SCHUNK 2048   // edges per block in sort kernels
#define MAXNBLK 1024  // max sort blocks supported by scan kernel LDS

// d_ws int32 layout:
//   [0..9]    celloff (exclusive prefix of cell totals, +total at [9])
//   [16..25]  blkoff  (main-kernel block ranges per cell, +total at [25])
//   [32 .. 32+NBLK*9)          per-(block,cell) counts -> global base offsets
//   [sorted_off .. sorted_off+E) sorted edge ids

__device__ __forceinline__ int cell_of(float ax, float ay) {
    float tx = (ax + 1.0f) * 1.5f;
    float ty = (ay + 1.0f) * 1.5f;
    int kx = (int)tx; if (kx > 2) kx = 2; if (kx < 0) kx = 0;
    int ky = (int)ty; if (ky > 2) ky = 2; if (ky < 0) ky = 0;
    return kx * 3 + ky;
}

__global__ __launch_bounds__(256) void hist_kernel(
    const float* __restrict__ attr, int E, int* __restrict__ counts)
{
    __shared__ int h[9];
    int b = blockIdx.x, t = threadIdx.x;
    if (t < 9) h[t] = 0;
    __syncthreads();
    int start = b * SCHUNK, end = min(start + SCHUNK, E);
    for (int e = start + t; e < end; e += 256) {
        float2 a = reinterpret_cast<const float2*>(attr)[e];
        atomicAdd(&h[cell_of(a.x, a.y)], 1);   // LDS atomic, per-CU
    }
    __syncthreads();
    if (t < 9) counts[b * 9 + t] = h[t];
}

__global__ __launch_bounds__(512) void scan_kernel(
    int* __restrict__ ws, int* __restrict__ counts, int nblk)
{
    __shared__ int s[MAXNBLK * 9];
    __shared__ int tot[9];
    __shared__ int coff[9];
    int n = nblk * 9;
    for (int i = threadIdx.x; i < n; i += 512) s[i] = counts[i];
    __syncthreads();
    if (threadIdx.x < 9) {                 // per-cell exclusive scan over blocks (LDS-serial)
        int c = threadIdx.x, run = 0;
        for (int b = 0; b < nblk; ++b) {
            int v = s[b * 9 + c];
            s[b * 9 + c] = run;
            run += v;
        }
        tot[c] = run;
    }
    __syncthreads();
    if (threadIdx.x == 0) {
        int off = 0, boff = 0;
        for (int c = 0; c < 9; ++c) {
            ws[c] = off;  coff[c] = off;
            ws[16 + c] = boff;
            off  += tot[c];
            boff += (tot[c] + EPB - 1) / EPB;
        }
        ws[9] = off;
        ws[16 + 9] = boff;
    }
    __syncthreads();
    for (int i = threadIdx.x; i < n; i += 512)
        counts[i] = s[i] + coff[i % 9];    // per-(block,cell) global bases
}

__global__ __launch_bounds__(256) void scatter_kernel(
    const float* __restrict__ attr, int E,
    const int* __restrict__ bases, int* __restrict__ sorted)
{
    __shared__ int cur[9];
    int b = blockIdx.x, t = threadIdx.x;
    if (t < 9) cur[t] = bases[b * 9 + t];
    __syncthreads();
    int start = b * SCHUNK, end = min(start + SCHUNK, E);
    for (int e = start + t; e < end; e += 256) {
        float2 a = reinterpret_cast<const float2*>(attr)[e];
        int c = cell_of(a.x, a.y);
        int pos = atomicAdd(&cur[c], 1);   // LDS atomic, per-CU
        sorted[pos] = e;
    }
}

#define FMA4(FE, I)                              \
    acc0 = fmaf((FE), wr[0][(I)], acc0);         \
    acc1 = fmaf((FE), wr[1][(I)], acc1);         \
    acc2 = fmaf((FE), wr[2][(I)], acc2);         \
    acc3 = fmaf((FE), wr[3][(I)], acc3);

__global__ __launch_bounds__(256) void bconv_main(
    const float* __restrict__ x_j, const int* __restrict__ ei,
    const float* __restrict__ attr, const float* __restrict__ weight,
    const int* __restrict__ ws, const int* __restrict__ sorted,
    float* __restrict__ out, int E)
{
    // map block -> (cell, local chunk)
    int b = blockIdx.x;
    const int* blkoff = ws + 16;
    if (b >= blkoff[9]) return;
    int c = 0;
    #pragma unroll
    for (int q = 1; q < 9; ++q) c += (b >= blkoff[q]) ? 1 : 0;
    int kx0 = c / 3, ky0 = c - 3 * (c / 3);
    int local  = b - blkoff[c];
    int cstart = ws[c];
    int cend   = ws[c + 1];
    int pstart = cstart + local * EPB;
    int pend   = min(pstart + EPB, cend);

    __shared__ float wl[4][F][F];    // 16 KB: this cell's 4 k-slices, [kk][i][o]
    __shared__ float featl[8][F];    // 1 KB: per-half-wave feature rows

    int t = threadIdx.x;
    #pragma unroll
    for (int r = 0; r < 4; ++r) {
        int k = (kx0 + (r >> 1)) * NB + (ky0 + (r & 1));
        float4 v = reinterpret_cast<const float4*>(weight + (size_t)k * F * F)[t];
        reinterpret_cast<float4*>(&wl[r][0][0])[t] = v;
    }
    __syncthreads();

    int lane  = t & 31;
    int eslot = t >> 5;

    float wr[4][F];                  // register copy: wr[kk][i] = W[k][i][lane]
    #pragma unroll
    for (int kk = 0; kk < 4; ++kk)
        #pragma unroll
        for (int i = 0; i < F; ++i)
            wr[kk][i] = wl[kk][i][lane];

    int p = pstart + eslot;
    if (p >= pend) return;           // uniform per half-wave

    int e    = sorted[p];
    int dst  = ei[e];
    int srcn = ei[E + e];
    float ax = attr[2 * e], ay = attr[2 * e + 1];
    float fv = x_j[(size_t)srcn * F + lane];

    while (true) {
        featl[eslot][lane] = fv;

        int pn = p + 8;
        bool nvalid = pn < pend;
        int dst2 = 0; float ax2 = 0.f, ay2 = 0.f, fv2 = 0.f;
        if (nvalid) {
            int e2 = sorted[pn];
            dst2 = ei[e2];
            int srcn2 = ei[E + e2];
            ax2  = attr[2 * e2]; ay2 = attr[2 * e2 + 1];
            fv2  = x_j[(size_t)srcn2 * F + lane];
        }

        float fx = (ax + 1.0f) * 1.5f - (float)kx0;
        float fy = (ay + 1.0f) * 1.5f - (float)ky0;
        float bx0 = 1.0f - fx, bx1 = fx;
        float by0 = 1.0f - fy, by1 = fy;

        float acc0 = 0.f, acc1 = 0.f, acc2 = 0.f, acc3 = 0.f;
        const float4* f4 = reinterpret_cast<const float4*>(&featl[eslot][0]);
        #pragma unroll
        for (int j = 0; j < 8; ++j) {
            float4 f = f4[j];
            FMA4(f.x, 4 * j + 0)
            FMA4(f.y, 4 * j + 1)
            FMA4(f.z, 4 * j + 2)
            FMA4(f.w, 4 * j + 3)
        }
        float msg = (bx0 * by0) * acc0 + (bx0 * by1) * acc1
                  + (bx1 * by0) * acc2 + (bx1 * by1) * acc3;
        atomicAdd(&out[(size_t)dst * F + lane], msg);

        if (!nvalid) break;
        p = pn; dst = dst2; ax = ax2; ay = ay2; fv = fv2;
    }
}

// Fallback: full 64KB weight in LDS, dynamic cell, no sorting.
__global__ __launch_bounds__(256) void bconv_fallback(
    const float* __restrict__ x_j, const int* __restrict__ ei,
    const float* __restrict__ attr, const float* __restrict__ weight,
    float* __restrict__ out, int E)
{
    __shared__ float wl[16 * F * F];
    __shared__ float featl[8][F];
    for (int idx = threadIdx.x; idx < 4096; idx += 256)
        reinterpret_cast<float4*>(wl)[idx] = reinterpret_cast<const float4*>(weight)[idx];
    __syncthreads();

    int lane = threadIdx.x & 31, eslot = threadIdx.x >> 5;
    for (int p = blockIdx.x * 8 + eslot; p < E; p += gridDim.x * 8) {
        int dst = ei[p], srcn = ei[E + p];
        float ax = attr[2 * p], ay = attr[2 * p + 1];
        featl[eslot][lane] = x_j[(size_t)srcn * F + lane];
        float tx = (ax + 1.0f) * 1.5f, ty = (ay + 1.0f) * 1.5f;
        int kx0 = (int)tx; if (kx0 > 2) kx0 = 2; if (kx0 < 0) kx0 = 0;
        int ky0 = (int)ty; if (ky0 > 2) ky0 = 2; if (ky0 < 0) ky0 = 0;
        float fx = tx - kx0, fy = ty - ky0;
        float bc[4] = { (1.0f - fx) * (1.0f - fy), (1.0f - fx) * fy,
                        fx * (1.0f - fy), fx * fy };
        float msg = 0.f;
        const float4* f4 = reinterpret_cast<const float4*>(&featl[eslot][0]);
        #pragma unroll
        for (int kk = 0; kk < 4; ++kk) {
            int k = (kx0 + (kk >> 1)) * NB + (ky0 + (kk & 1));
            const float* wk = wl + k * F * F;
            float acc = 0.f;
            #pragma unroll
            for (int j = 0; j < 8; ++j) {
                float4 f = f4[j];
                acc = fmaf(f.x, wk[(4 * j + 0) * F + lane], acc);
                acc = fmaf(f.y, wk[(4 * j + 1) * F + lane], acc);
                acc = fmaf(f.z, wk[(4 * j + 2) * F + lane], acc);
                acc = fmaf(f.w, wk[(4 * j + 3) * F + lane], acc);
            }
            msg = fmaf(bc[kk], acc, msg);
        }
        atomicAdd(&out[(size_t)dst * F + lane], msg);
    }
}

extern "C" void kernel_launch(void* const* d_in, const int* in_sizes, int n_in,
                              void* d_out, int out_size, void* d_ws, size_t ws_size,
                              hipStream_t stream) {
    const float* x_j    = (const float*)d_in[1];
    const int*   ei     = (const int*)d_in[2];
    const float* attr   = (const float*)d_in[3];
    const float* weight = (const float*)d_in[4];
    float* out = (float*)d_out;
    int E = in_sizes[2] / 2;

    hipMemsetAsync(d_out, 0, (size_t)out_size * sizeof(float), stream);

    int nblk_sort = (E + SCHUNK - 1) / SCHUNK;
    int sorted_off = 32 + ((nblk_sort * 9 + 15) & ~15);
    size_t ws_need = (size_t)(sorted_off + E) * sizeof(int);

    if (nblk_sort <= MAXNBLK && ws_size >= ws_need) {
        int* ws      = (int*)d_ws;
        int* counts  = ws + 32;
        int* sorted  = ws + sorted_off;
        hist_kernel<<<nblk_sort, 256, 0, stream>>>(attr, E, counts);
        scan_kernel<<<1, 512, 0, stream>>>(ws, counts, nblk_sort);
        scatter_kernel<<<nblk_sort, 256, 0, stream>>>(attr, E, counts, sorted);
        int nblk_main = (E + EPB - 1) / EPB + 9;
        bconv_main<<<nblk_main, 256, 0, stream>>>(x_j, ei, attr, weight, ws, sorted, out, E);
    } else {
        bconv_fallback<<<2048, 256, 0, stream>>>(x_j, ei, attr, weight, out, E);
    }
}

// Round 3
// 113.550 us; speedup vs baseline: 51.9603x; 2.2275x over previous
//
#include <hip/hip_runtime.h>

typedef short short8 __attribute__((ext_vector_type(8)));
typedef float f32x4 __attribute__((ext_vector_type(4)));

#define NB 4
#define F 32          // F_IN == F_OUT == 32
#define EPB 512       // edges per block in main kernel
#define SCHUNK 2048   // edges per block in sort kernels
#define MAXNBLK 1024  // max sort blocks supported by scan kernel LDS

// d_ws int32 layout:
//   [0..9]    celloff (+total at [9])
//   [16..25]  blkoff  (+total at [25])
//   [32 .. 32+NBLK*9)   per-(block,cell) counts -> global base offsets
//   [sorted_off ..)     sorted edge ids

__device__ __forceinline__ int cell_of(float ax, float ay) {
    float tx = (ax + 1.0f) * 1.5f;
    float ty = (ay + 1.0f) * 1.5f;
    int kx = (int)tx; if (kx > 2) kx = 2; if (kx < 0) kx = 0;
    int ky = (int)ty; if (ky > 2) ky = 2; if (ky < 0) ky = 0;
    return kx * 3 + ky;
}

__device__ __forceinline__ short f2bf(float f) {   // RNE f32->bf16 (finite inputs)
    unsigned u = __float_as_uint(f);
    unsigned r = (u + 0x7FFFu + ((u >> 16) & 1u)) >> 16;
    return (short)r;
}

__global__ __launch_bounds__(256) void hist_kernel(
    const float* __restrict__ attr, int E, int* __restrict__ counts)
{
    __shared__ int h[9];
    int b = blockIdx.x, t = threadIdx.x;
    if (t < 9) h[t] = 0;
    __syncthreads();
    int start = b * SCHUNK, end = min(start + SCHUNK, E);
    for (int e = start + t; e < end; e += 256) {
        float2 a = reinterpret_cast<const float2*>(attr)[e];
        atomicAdd(&h[cell_of(a.x, a.y)], 1);   // LDS atomic
    }
    __syncthreads();
    if (t < 9) counts[b * 9 + t] = h[t];
}

__global__ __launch_bounds__(512) void scan_kernel(
    int* __restrict__ ws, int* __restrict__ counts, int nblk)
{
    __shared__ int s[MAXNBLK * 9];
    __shared__ int tot[9];
    __shared__ int coff[9];
    int n = nblk * 9;
    for (int i = threadIdx.x; i < n; i += 512) s[i] = counts[i];
    __syncthreads();
    if (threadIdx.x < 9) {
        int c = threadIdx.x, run = 0;
        for (int b = 0; b < nblk; ++b) {
            int v = s[b * 9 + c];
            s[b * 9 + c] = run;
            run += v;
        }
        tot[c] = run;
    }
    __syncthreads();
    if (threadIdx.x == 0) {
        int off = 0, boff = 0;
        for (int c = 0; c < 9; ++c) {
            ws[c] = off;  coff[c] = off;
            ws[16 + c] = boff;
            off  += tot[c];
            boff += (tot[c] + EPB - 1) / EPB;
        }
        ws[9] = off;
        ws[16 + 9] = boff;
    }
    __syncthreads();
    for (int i = threadIdx.x; i < n; i += 512)
        counts[i] = s[i] + coff[i % 9];
}

__global__ __launch_bounds__(256) void scatter_kernel(
    const float* __restrict__ attr, int E,
    const int* __restrict__ bases, int* __restrict__ sorted)
{
    __shared__ int cur[9];
    int b = blockIdx.x, t = threadIdx.x;
    if (t < 9) cur[t] = bases[b * 9 + t];
    __syncthreads();
    int start = b * SCHUNK, end = min(start + SCHUNK, E);
    for (int e = start + t; e < end; e += 256) {
        float2 a = reinterpret_cast<const float2*>(attr)[e];
        int c = cell_of(a.x, a.y);
        int pos = atomicAdd(&cur[c], 1);
        sorted[pos] = e;
    }
}

// MFMA main kernel: per cell, msg[16e x 32o] = A'[16e x 128] * W'[128 x 32]
// where A'[e][kk*32+i] = b_kk(e) * feat[e][i]  (basis folded into A).
__global__ __launch_bounds__(256) void bconv_mfma(
    const float* __restrict__ x_j, const int* __restrict__ ei,
    const float* __restrict__ attr, const float* __restrict__ weight,
    const int* __restrict__ ws, const int* __restrict__ sorted,
    float* __restrict__ out, int E)
{
    int b = blockIdx.x;
    const int* blkoff = ws + 16;
    if (b >= blkoff[9]) return;
    int c = 0;
    #pragma unroll
    for (int q = 1; q < 9; ++q) c += (b >= blkoff[q]) ? 1 : 0;
    int kx0 = c / 3, ky0 = c - 3 * (c / 3);
    int local  = b - blkoff[c];
    int cstart = ws[c];
    int cend   = ws[c + 1];
    int pstart = cstart + local * EPB;
    int pend   = min(pstart + EPB, cend);

    int t     = threadIdx.x;
    int wid   = t >> 6;
    int lane  = t & 63;
    int row16 = lane & 15;   // mfma row (A) / col (B,C)
    int hi    = lane >> 4;   // k-group 0..3
    int edge4 = lane >> 2;   // staging: edge slot 0..15
    int chunk = lane & 3;    // staging: feat chunk (8 floats)

    // wave-private LDS; write (chunk,edge4) and read (hi,row16) are both
    // bijective over 64 distinct 16B slots -> conflict-free b128 ops.
    __shared__ short featb[4][4][4][16][8];  // [wave][kk][kgrp][edge][8 bf16] = 16 KB
    __shared__ int   dstl[4][16];

    // B fragments in registers: wb[kk][nhalf], k = 8*hi+j, col = row16+16*n
    short8 wb[4][2];
    #pragma unroll
    for (int kk = 0; kk < 4; ++kk) {
        int ks = (kx0 + (kk >> 1)) * NB + (ky0 + (kk & 1));
        const float* wp = weight + (size_t)ks * F * F;
        #pragma unroll
        for (int n = 0; n < 2; ++n) {
            short8 v;
            #pragma unroll
            for (int j = 0; j < 8; ++j)
                v[j] = f2bf(wp[(8 * hi + j) * F + row16 + 16 * n]);
            wb[kk][n] = v;
        }
    }

    int wstart = pstart + wid * (EPB / 4);
    int wend   = min(wstart + (EPB / 4), pend);
    if (wstart >= wend) return;

    int   dst0; float ax0, ay0; float4 fa0, fb0; bool v0;
    auto load = [&](int tstart, int& dst, float& ax, float& ay,
                    float4& fa, float4& fb, bool& valid) {
        int p = tstart + edge4;
        valid = p < wend;
        int pp = valid ? p : wstart;
        int e  = sorted[pp];
        dst = ei[e];
        int srcn = ei[E + e];
        float2 a = reinterpret_cast<const float2*>(attr)[e];
        ax = a.x; ay = a.y;
        const float4* xr = reinterpret_cast<const float4*>(x_j + (size_t)srcn * F);
        fa = xr[chunk * 2];
        fb = xr[chunk * 2 + 1];
    };

    int ntiles = (wend - wstart + 15) >> 4;
    load(wstart, dst0, ax0, ay0, fa0, fb0, v0);

    for (int tt = 0; tt < ntiles; ++tt) {
        // stage current tile: scale by basis coeffs, convert, LDS
        float fx  = (ax0 + 1.0f) * 1.5f - (float)kx0;   // in [0,1] for this cell
        float fy  = (ay0 + 1.0f) * 1.5f - (float)ky0;
        float bxa = 1.0f - fx, bya = 1.0f - fy;
        float bc[4] = { bxa * bya, bxa * fy, fx * bya, fx * fy };
        float fl[8] = { fa0.x, fa0.y, fa0.z, fa0.w, fb0.x, fb0.y, fb0.z, fb0.w };
        #pragma unroll
        for (int kk = 0; kk < 4; ++kk) {
            float s = v0 ? bc[kk] : 0.0f;
            short8 sv;
            #pragma unroll
            for (int j = 0; j < 8; ++j) sv[j] = f2bf(fl[j] * s);
            *reinterpret_cast<short8*>(&featb[wid][kk][chunk][edge4][0]) = sv;
        }
        if (chunk == 0) dstl[wid][edge4] = v0 ? dst0 : -1;

        // prefetch next tile (global loads overlap MFMA; vmcnt != lgkmcnt)
        if (tt + 1 < ntiles)
            load(wstart + (tt + 1) * 16, dst0, ax0, ay0, fa0, fb0, v0);

        // 8 MFMAs: acc = A'(16x128) * W'(128x32)
        f32x4 acc0 = {0.f, 0.f, 0.f, 0.f}, acc1 = {0.f, 0.f, 0.f, 0.f};
        #pragma unroll
        for (int kk = 0; kk < 4; ++kk) {
            short8 a = *reinterpret_cast<const short8*>(&featb[wid][kk][hi][row16][0]);
            acc0 = __builtin_amdgcn_mfma_f32_16x16x32_bf16(a, wb[kk][0], acc0, 0, 0, 0);
            acc1 = __builtin_amdgcn_mfma_f32_16x16x32_bf16(a, wb[kk][1], acc1, 0, 0, 0);
        }

        // scatter: C row = 4*hi + r (edge), col = row16 (+16)
        #pragma unroll
        for (int r = 0; r < 4; ++r) {
            int d = dstl[wid][hi * 4 + r];
            if (d >= 0) {
                atomicAdd(&out[(size_t)d * F + row16],      acc0[r]);
                atomicAdd(&out[(size_t)d * F + 16 + row16], acc1[r]);
            }
        }
    }
}

// Fallback (ws too small): f32 VALU path, full weight in LDS.
__global__ __launch_bounds__(256) void bconv_fallback(
    const float* __restrict__ x_j, const int* __restrict__ ei,
    const float* __restrict__ attr, const float* __restrict__ weight,
    float* __restrict__ out, int E)
{
    __shared__ float wl[16 * F * F];
    __shared__ float featl[8][F];
    for (int idx = threadIdx.x; idx < 4096; idx += 256)
        reinterpret_cast<float4*>(wl)[idx] = reinterpret_cast<const float4*>(weight)[idx];
    __syncthreads();

    int lane = threadIdx.x & 31, eslot = threadIdx.x >> 5;
    for (int p = blockIdx.x * 8 + eslot; p < E; p += gridDim.x * 8) {
        int dst = ei[p], srcn = ei[E + p];
        float ax = attr[2 * p], ay = attr[2 * p + 1];
        featl[eslot][lane] = x_j[(size_t)srcn * F + lane];
        float tx = (ax + 1.0f) * 1.5f, ty = (ay + 1.0f) * 1.5f;
        int kx0 = (int)tx; if (kx0 > 2) kx0 = 2; if (kx0 < 0) kx0 = 0;
        int ky0 = (int)ty; if (ky0 > 2) ky0 = 2; if (ky0 < 0) ky0 = 0;
        float fx = tx - kx0, fy = ty - ky0;
        float bcv[4] = { (1.0f - fx) * (1.0f - fy), (1.0f - fx) * fy,
                         fx * (1.0f - fy), fx * fy };
        float msg = 0.f;
        const float4* f4 = reinterpret_cast<const float4*>(&featl[eslot][0]);
        #pragma unroll
        for (int kk = 0; kk < 4; ++kk) {
            int k = (kx0 + (kk >> 1)) * NB + (ky0 + (kk & 1));
            const float* wk = wl + k * F * F;
            float acc = 0.f;
            #pragma unroll
            for (int j = 0; j < 8; ++j) {
                float4 f = f4[j];
                acc = fmaf(f.x, wk[(4 * j + 0) * F + lane], acc);
                acc = fmaf(f.y, wk[(4 * j + 1) * F + lane], acc);
                acc = fmaf(f.z, wk[(4 * j + 2) * F + lane], acc);
                acc = fmaf(f.w, wk[(4 * j + 3) * F + lane], acc);
            }
            msg = fmaf(bcv[kk], acc, msg);
        }
        atomicAdd(&out[(size_t)dst * F + lane], msg);
    }
}

extern "C" void kernel_launch(void* const* d_in, const int* in_sizes, int n_in,
                              void* d_out, int out_size, void* d_ws, size_t ws_size,
                              hipStream_t stream) {
    const float* x_j    = (const float*)d_in[1];
    const int*   ei     = (const int*)d_in[2];
    const float* attr   = (const float*)d_in[3];
    const float* weight = (const float*)d_in[4];
    float* out = (float*)d_out;
    int E = in_sizes[2] / 2;

    hipMemsetAsync(d_out, 0, (size_t)out_size * sizeof(float), stream);

    int nblk_sort = (E + SCHUNK - 1) / SCHUNK;
    int sorted_off = 32 + ((nblk_sort * 9 + 15) & ~15);
    size_t ws_need = (size_t)(sorted_off + E) * sizeof(int);

    if (nblk_sort <= MAXNBLK && ws_size >= ws_need) {
        int* ws      = (int*)d_ws;
        int* counts  = ws + 32;
        int* sorted  = ws + sorted_off;
        hist_kernel<<<nblk_sort, 256, 0, stream>>>(attr, E, counts);
        scan_kernel<<<1, 512, 0, stream>>>(ws, counts, nblk_sort);
        scatter_kernel<<<nblk_sort, 256, 0, stream>>>(attr, E, counts, sorted);
        int nblk_main = (E + EPB - 1) / EPB + 9;
        bconv_mfma<<<nblk_main, 256, 0, stream>>>(x_j, ei, attr, weight, ws, sorted, out, E);
    } else {
        bconv_fallback<<<2048, 256, 0, stream>>>(x_j, ei, attr, weight, out, E);
    }
}